// Round 8
// baseline (1624.651 us; speedup 1.0000x reference)
//
#include <hip/hip_runtime.h>
#include <math.h>

#define BB 128
#define TT 2048
#define II 64
#define HH 128
#define EE (II + HH)    // 192 combined operand values [x_t ; h_{t-1}]

typedef _Float16 f16x8 __attribute__((ext_vector_type(8)));
typedef _Float16 h4v  __attribute__((ext_vector_type(4)));
typedef float    f32x4 __attribute__((ext_vector_type(4)));

// Opaque load: value is asm-defined -> regalloc cannot rematerialize the
// global load inside the t-loop (round-4-proven).
#define LOADQ(dst, ptr)                                                      \
    asm volatile("global_load_dwordx4 %0, %1, off\n\ts_waitcnt vmcnt(0)"     \
                 : "=&v"(dst) : "v"(ptr) : "memory")

__device__ __forceinline__ float fsig(float z) {
    return 1.0f / (1.0f + __expf(-z));
}
__device__ __forceinline__ float ftanh(float z) {
    float e = __expf(2.0f * z);
    return 1.0f - 2.0f / (e + 1.0f);
}

// Round-8: dots moved to the MFMA pipe. gates = W'[512x192] . e[192] as
// mfma_f32_16x16x32_f16 with B = e broadcast to all 16 cols (B-frag depends
// only on lane>>4 -> uniform LDS reads). Wave w owns gate-tiles {w,w+8,w+16,
// w+24} = gates i,f,g,o of elements 16w..16w+15; 24 MFMA/wave/step. Weights
// are A-frags (LOADQ-pinned, read in place by MFMA -> zero per-step VALU).
// Epilogue dense per lane via reg-pick (C layout: col=lane&15,
// row=(lane>>4)*4+reg [m89/m91]): lane handles element 16w+4*(l>>4)+(l&3).
// Round-7 evidence: VALU pipe saturated (76% active-CU VALUBusy) by dot+glue
// instructions -> offload to the separate MFMA pipe (m114: full co-issue).
__global__ __launch_bounds__(512) __attribute__((amdgpu_waves_per_eu(2, 2)))
void lstm_mfma(
    const float* __restrict__ x,      // [B,T,I]
    const float* __restrict__ W_ih,   // [4H,I]
    const float* __restrict__ W_hh,   // [4H,H]
    const float* __restrict__ b_ih,   // [4H]
    const float* __restrict__ b_hh,   // [4H]
    float* __restrict__ out)          // [B,T,H]
{
    const int b  = blockIdx.x;
    const int j  = threadIdx.x;
    const int w  = j >> 6;            // wave 0..7
    const int l  = j & 63;            // lane
    const int lr = l & 15;            // A-frag row within 16-row tile
    const int lk = l >> 4;            // k-group 0..3

    // ---- A-fragments: a[g][kt] = W'-tile [16 rows x 32 k], rows 128g+16w+lr,
    // combined cols cc = 32kt + 8lk .. +8 (cc<64 -> W_ih, else W_hh).
    // 8-col chunks never straddle the 64-boundary (cc % 8 == 0).
    f16x8 a[4][6];
    #pragma unroll
    for (int g = 0; g < 4; ++g) {
        const int row = 128 * g + 16 * w + lr;
        #pragma unroll
        for (int kt = 0; kt < 6; ++kt) {
            const int cc = 32 * kt + 8 * lk;
            const float* p = (cc < II) ? (W_ih + (size_t)row * II + cc)
                                       : (W_hh + (size_t)row * HH + (cc - II));
            float4 v0, v1;
            LOADQ(v0, p);
            LOADQ(v1, p + 4);
            f16x8 q;
            q[0] = (_Float16)v0.x; q[1] = (_Float16)v0.y;
            q[2] = (_Float16)v0.z; q[3] = (_Float16)v0.w;
            q[4] = (_Float16)v1.x; q[5] = (_Float16)v1.y;
            q[6] = (_Float16)v1.z; q[7] = (_Float16)v1.w;
            a[g][kt] = q;
        }
    }

    // ---- bias fragments in C/D layout: bfr[g][r] = bias of row 128g+16w+4lk+r
    // (seeded as MFMA C-input each step -> no per-step adds/movs)
    f32x4 bfr[4];
    #pragma unroll
    for (int g = 0; g < 4; ++g)
        #pragma unroll
        for (int r = 0; r < 4; ++r) {
            const int row = 128 * g + 16 * w + 4 * lk + r;
            bfr[g][r] = b_ih[row] + b_hh[row];
        }

    __shared__ __align__(16) _Float16 ebuf[2][EE];  // [x_t ; h_{t-1}] f16, dbuf

    const int  em = 16 * w + 4 * lk + (l & 3);  // element this lane updates
    const bool wr = ((l & 12) == 0);            // 16 writer lanes per wave

    float c = 0.0f;                   // cell state of element em (x4 redundant)
    if (j < HH) ebuf[0][II + j] = (_Float16)0.0f;

    const float4* xg = reinterpret_cast<const float4*>(x + (size_t)b * TT * II);
    float4 xq0, xq1, xq2, xq3;        // depth-4 x prefetch (16 lanes)
    if (j < II / 4) {
        float4 v = xg[j];
        h4v q; q[0] = (_Float16)v.x; q[1] = (_Float16)v.y;
               q[2] = (_Float16)v.z; q[3] = (_Float16)v.w;
        reinterpret_cast<h4v*>(&ebuf[0][0])[j] = q;
        xq0 = xg[1 * (II / 4) + j];
        xq1 = xg[2 * (II / 4) + j];
        xq2 = xg[3 * (II / 4) + j];
        xq3 = xg[4 * (II / 4) + j];
    }
    float* outb = out + (size_t)b * TT * HH;
    __syncthreads();

#define STEP(CUR, NXT, T, XQ)                                                 \
    {                                                                         \
        /* x_{T+1}: loaded 4 steps ago -> convert + LDS write at step TOP */  \
        if (j < II / 4) {                                                     \
            if ((T) + 1 < TT) {                                               \
                h4v q; q[0] = (_Float16)XQ.x; q[1] = (_Float16)XQ.y;          \
                       q[2] = (_Float16)XQ.z; q[3] = (_Float16)XQ.w;          \
                reinterpret_cast<h4v*>(&ebuf[NXT][0])[j] = q;                 \
            }                                                                 \
            if ((T) + 5 < TT)                                                 \
                XQ = xg[(size_t)((T) + 5) * (II / 4) + j];                    \
        }                                                                     \
        /* B-frags: e[k-slice] broadcast to all cols (addr depends on lk) */  \
        const f16x8 bf0 = *reinterpret_cast<const f16x8*>(&ebuf[CUR][  0 + 8*lk]); \
        const f16x8 bf1 = *reinterpret_cast<const f16x8*>(&ebuf[CUR][ 32 + 8*lk]); \
        const f16x8 bf2 = *reinterpret_cast<const f16x8*>(&ebuf[CUR][ 64 + 8*lk]); \
        const f16x8 bf3 = *reinterpret_cast<const f16x8*>(&ebuf[CUR][ 96 + 8*lk]); \
        const f16x8 bf4 = *reinterpret_cast<const f16x8*>(&ebuf[CUR][128 + 8*lk]); \
        const f16x8 bf5 = *reinterpret_cast<const f16x8*>(&ebuf[CUR][160 + 8*lk]); \
        f32x4 ac[4];                                                          \
        _Pragma("unroll")                                                     \
        for (int g = 0; g < 4; ++g)                                           \
            ac[g] = __builtin_amdgcn_mfma_f32_16x16x32_f16(a[g][0], bf0, bfr[g], 0, 0, 0); \
        _Pragma("unroll")                                                     \
        for (int g = 0; g < 4; ++g)                                           \
            ac[g] = __builtin_amdgcn_mfma_f32_16x16x32_f16(a[g][1], bf1, ac[g], 0, 0, 0); \
        _Pragma("unroll")                                                     \
        for (int g = 0; g < 4; ++g)                                           \
            ac[g] = __builtin_amdgcn_mfma_f32_16x16x32_f16(a[g][2], bf2, ac[g], 0, 0, 0); \
        _Pragma("unroll")                                                     \
        for (int g = 0; g < 4; ++g)                                           \
            ac[g] = __builtin_amdgcn_mfma_f32_16x16x32_f16(a[g][3], bf3, ac[g], 0, 0, 0); \
        _Pragma("unroll")                                                     \
        for (int g = 0; g < 4; ++g)                                           \
            ac[g] = __builtin_amdgcn_mfma_f32_16x16x32_f16(a[g][4], bf4, ac[g], 0, 0, 0); \
        _Pragma("unroll")                                                     \
        for (int g = 0; g < 4; ++g)                                           \
            ac[g] = __builtin_amdgcn_mfma_f32_16x16x32_f16(a[g][5], bf5, ac[g], 0, 0, 0); \
        /* reg-pick r = l&3: lane gets all 4 gates of element em */           \
        float pv[4];                                                          \
        _Pragma("unroll")                                                     \
        for (int g = 0; g < 4; ++g) {                                         \
            const float t0 = (l & 1) ? ac[g][1] : ac[g][0];                   \
            const float t1 = (l & 1) ? ac[g][3] : ac[g][2];                   \
            pv[g] = (l & 2) ? t1 : t0;                                        \
        }                                                                     \
        const float iv = fsig(pv[0]);                                         \
        const float fv = fsig(pv[1]);                                         \
        const float gv = ftanh(pv[2]);                                        \
        const float ov = fsig(pv[3]);                                         \
        c = fv * c + iv * gv;                                                 \
        const float h = ov * ftanh(c);                                        \
        if (wr) {                                                             \
            ebuf[NXT][II + em] = (_Float16)h;                                 \
            outb[(size_t)(T) * HH + em] = h;                                  \
        }                                                                     \
        __syncthreads();                                                      \
    }

    for (int t = 0; t < TT; t += 4) {
        STEP(0, 1, t,     xq0);
        STEP(1, 0, t + 1, xq1);
        STEP(0, 1, t + 2, xq2);
        STEP(1, 0, t + 3, xq3);
    }
#undef STEP
}

extern "C" void kernel_launch(void* const* d_in, const int* in_sizes, int n_in,
                              void* d_out, int out_size, void* d_ws, size_t ws_size,
                              hipStream_t stream) {
    const float* x    = (const float*)d_in[0];
    const float* W_ih = (const float*)d_in[1];
    const float* W_hh = (const float*)d_in[2];
    const float* b_ih = (const float*)d_in[3];
    const float* b_hh = (const float*)d_in[4];
    float* out = (float*)d_out;
    (void)d_ws; (void)ws_size; (void)in_sizes; (void)n_in; (void)out_size;
    hipLaunchKernelGGL(lstm_mfma, dim3(BB), dim3(512), 0, stream,
                       x, W_ih, W_hh, b_ih, b_hh, out);
}